// Round 7
// baseline (699.933 us; speedup 1.0000x reference)
//
#include <hip/hip_runtime.h>

// ---------------------------------------------------------------------------
// Transformer block, B=4 T=2048 C=1024 H=16 hd=64 DFF=4096, bf16 MFMA compute.
// R7: AITER-flatmm-style GEMM K-loop — B (weights) loaded direct from global
// into registers (no LDS), A staged via global_load_lds into DOUBLE-buffered
// LDS, both prefetched one full iteration ahead so the pre-barrier vmcnt(0)
// drain waits on iteration-old loads (cheap). 32x32 MFMA 2x2/wave kept.
// ---------------------------------------------------------------------------

typedef __attribute__((ext_vector_type(8))) short short8;   // 8 bf16 = 4 VGPRs
typedef __attribute__((ext_vector_type(4))) float fx4;      // 16x16 MFMA acc
typedef __attribute__((ext_vector_type(16))) float fx16;    // 32x32 MFMA acc

__device__ __forceinline__ unsigned short f2bf(float f) {
    union { float f; unsigned u; } v; v.f = f;
    unsigned r = v.u + 0x7fffu + ((v.u >> 16) & 1u);  // RNE
    return (unsigned short)(r >> 16);
}

__device__ __forceinline__ float fexp2(float x) {
#if __has_builtin(__builtin_amdgcn_exp2f)
    return __builtin_amdgcn_exp2f(x);
#else
    return __expf(x * 0.69314718055994531f);
#endif
}

// pack two f32 -> two bf16 (truncation) in one v_perm_b32
__device__ __forceinline__ unsigned pack_trunc(float lo, float hi) {
    return __builtin_amdgcn_perm(__float_as_uint(hi), __float_as_uint(lo),
                                 0x07060302u);
}

// async global->LDS, 16B per lane; LDS dest = wave-uniform base + lane*16
__device__ __forceinline__ void ld_lds16(const void* g, void* l) {
    __builtin_amdgcn_global_load_lds(
        (const __attribute__((address_space(1))) unsigned int*)g,
        (__attribute__((address_space(3))) unsigned int*)l, 16, 0, 0);
}

// ---------------------------------------------------------------------------
// All four weight transposes in one launch. in [R][Cn] f32 -> out [Cn][R] bf16
// ---------------------------------------------------------------------------
__global__ __launch_bounds__(256) void transpose_all(
    const float* __restrict__ w0, unsigned short* __restrict__ o0,
    const float* __restrict__ w1, unsigned short* __restrict__ o1,
    const float* __restrict__ w2, unsigned short* __restrict__ o2,
    const float* __restrict__ w3, unsigned short* __restrict__ o3)
{
    __shared__ float tile[32][33];
    int b = blockIdx.x;
    const float* in; unsigned short* out; int R, Cn;
    if (b < 3072)      { in = w0; out = o0; R = 1024; Cn = 3072; }
    else if (b < 4096) { b -= 3072; in = w1; out = o1; R = 1024; Cn = 1024; }
    else if (b < 8192) { b -= 4096; in = w2; out = o2; R = 1024; Cn = 4096; }
    else               { b -= 8192; in = w3; out = o3; R = 4096; Cn = 1024; }
    int tilesX = Cn >> 5;
    int c0 = (b % tilesX) * 32, r0 = (b / tilesX) * 32;
    int tx = threadIdx.x, ty = threadIdx.y;                 // block (32,8)
    for (int i = 0; i < 4; ++i)
        tile[ty + i * 8][tx] = in[(size_t)(r0 + ty + i * 8) * Cn + c0 + tx];
    __syncthreads();
    for (int i = 0; i < 4; ++i)
        out[(size_t)(c0 + ty + i * 8) * R + r0 + tx] = f2bf(tile[tx][ty + i * 8]);
}

// ---------------------------------------------------------------------------
// LayerNorm row kernel: fp32 in -> bf16 out.  C = 1024, block = 256.
// ---------------------------------------------------------------------------
__global__ __launch_bounds__(256) void layernorm_bf16(
    const float* __restrict__ x, const float* __restrict__ g,
    const float* __restrict__ bb, unsigned short* __restrict__ out)
{
    const int C = 1024;
    int row = blockIdx.x;
    const float* xr = x + (size_t)row * C;
    float4 v = ((const float4*)xr)[threadIdx.x];
    float s  = v.x + v.y + v.z + v.w;
    float ss = v.x * v.x + v.y * v.y + v.z * v.z + v.w * v.w;
    for (int off = 32; off >= 1; off >>= 1) {
        s  += __shfl_xor(s,  off);
        ss += __shfl_xor(ss, off);
    }
    __shared__ float sbuf[2][4];
    int wave = threadIdx.x >> 6;
    if ((threadIdx.x & 63) == 0) { sbuf[0][wave] = s; sbuf[1][wave] = ss; }
    __syncthreads();
    s  = sbuf[0][0] + sbuf[0][1] + sbuf[0][2] + sbuf[0][3];
    ss = sbuf[1][0] + sbuf[1][1] + sbuf[1][2] + sbuf[1][3];
    float mu   = s * (1.0f / C);
    float var  = ss * (1.0f / C) - mu * mu;
    float rstd = rsqrtf(var + 1e-5f);
    int i = threadIdx.x * 4;
    ushort4 o;
    o.x = f2bf((v.x - mu) * rstd * g[i + 0] + bb[i + 0]);
    o.y = f2bf((v.y - mu) * rstd * g[i + 1] + bb[i + 1]);
    o.z = f2bf((v.z - mu) * rstd * g[i + 2] + bb[i + 2]);
    o.w = f2bf((v.w - mu) * rstd * g[i + 3] + bb[i + 3]);
    ((ushort4*)(out + (size_t)row * C))[threadIdx.x] = o;
}

// ---------------------------------------------------------------------------
// bf16 GEMM, C = A[M,K] @ B[K,N], B given transposed (Bt[N,K]).
// 128x128 tile, BK=64. A: double-buffered LDS via global_load_lds (swizzled
// slot=(chunk+row)&7). B: direct global->register fragments (no LDS).
// Both prefetched one iteration ahead. Inner: mfma_f32_32x32x16_bf16 2x2.
// C/D: col=lane&31, row=(reg&3)+8*(reg>>2)+4*(lane>>5)  [m74/m101 verified].
// EPI 0: +bias, scatter to Q*scl[BH,T,64] / K[BH,T,64] / Vt[BH,64,T] (bf16)
// EPI 1: +bias +resid(f32) -> f32 out
// EPI 2: +bias, GELU -> bf16 out
// ---------------------------------------------------------------------------
template <int EPI>
__global__ __launch_bounds__(256) void gemm_bt(
    const unsigned short* __restrict__ A, const unsigned short* __restrict__ Bt,
    const float* __restrict__ bias, const float* __restrict__ resid,
    void* __restrict__ out0, void* __restrict__ out1, void* __restrict__ out2,
    int M, int N, int K)
{
    __shared__ unsigned short As[2][128 * 64];
    const int bm = blockIdx.y * 128, bn = blockIdx.x * 128;
    const int t = threadIdx.x, wave = t >> 6, lane = t & 63;
    const int wm = (wave >> 1) * 64, wn = (wave & 1) * 64;
    const int l32 = lane & 31, half = lane >> 5;

    // A staging offsets (4 x 16B slots per thread).
    int goff[4], loff[4];
    #pragma unroll
    for (int c = 0; c < 4; ++c) {
        int idx = t + c * 256;                // 0..1023, 16B per slot
        int row = idx >> 3, ps = idx & 7;
        int p = (ps - row) & 7;               // global chunk held at slot ps
        goff[c] = row * K + p * 8;
        loff[c] = idx * 8;
    }
    // A fragment LDS offsets [tile][kstep] (swizzled).
    int aoffs[2][4];
    #pragma unroll
    for (int i = 0; i < 2; ++i)
        #pragma unroll
        for (int s = 0; s < 4; ++s) {
            int ra = wm + i * 32 + l32;
            aoffs[i][s] = ra * 64 + (((s * 2 + half + ra) & 7) << 3);
        }
    // B fragment global element offsets [tile][kstep] (from advancing Bb).
    int bgo[2][4];
    #pragma unroll
    for (int i = 0; i < 2; ++i)
        #pragma unroll
        for (int s = 0; s < 4; ++s)
            bgo[i][s] = (wn + i * 32 + l32) * K + s * 16 + half * 8;

    const unsigned short* Ab = A + (size_t)bm * K;   // += 64 per iter
    const unsigned short* Bb = Bt + (size_t)bn * K;  // += 64 per iter

    fx16 acc[2][2];
    #pragma unroll
    for (int mi = 0; mi < 2; ++mi)
        #pragma unroll
        for (int ni = 0; ni < 2; ++ni)
            acc[mi][ni] = 0.0f;

    short8 bcur[2][4], bnxt[2][4];

    auto prefetch = [&](int buf, short8 (&bf)[2][4]) {
        #pragma unroll
        for (int c = 0; c < 4; ++c)
            ld_lds16(Ab + goff[c], &As[buf][loff[c]]);
        #pragma unroll
        for (int i = 0; i < 2; ++i)
            #pragma unroll
            for (int s = 0; s < 4; ++s)
                bf[i][s] = *(const short8*)(Bb + bgo[i][s]);
        Ab += 64; Bb += 64;
    };
    auto compute = [&](int buf, short8 (&bf)[2][4]) {
        #pragma unroll
        for (int s = 0; s < 4; ++s) {
            short8 a0 = *(const short8*)&As[buf][aoffs[0][s]];
            short8 a1 = *(const short8*)&As[buf][aoffs[1][s]];
            acc[0][0] = __builtin_amdgcn_mfma_f32_32x32x16_bf16(a0, bf[0][s], acc[0][0], 0, 0, 0);
            acc[0][1] = __builtin_amdgcn_mfma_f32_32x32x16_bf16(a0, bf[1][s], acc[0][1], 0, 0, 0);
            acc[1][0] = __builtin_amdgcn_mfma_f32_32x32x16_bf16(a1, bf[0][s], acc[1][0], 0, 0, 0);
            acc[1][1] = __builtin_amdgcn_mfma_f32_32x32x16_bf16(a1, bf[1][s], acc[1][1], 0, 0, 0);
        }
    };

    const int nit = K >> 6;                   // 16 or 64 (always even)
    prefetch(0, bcur);
    __syncthreads();                          // drain staging(0)
    for (int it = 0; it < nit; it += 2) {
        if (it + 1 < nit) prefetch(1, bnxt);  // loads for iter it+1
        compute(0, bcur);                     // iter it
        __syncthreads();                      // staging(it+1) landed; As[0] free
        if (it + 1 < nit) {
            if (it + 2 < nit) prefetch(0, bcur);
            compute(1, bnxt);                 // iter it+1
            __syncthreads();
        }
    }

    // Epilogue. C/D: col=lane&31, row=(reg&3)+8*(reg>>2)+4*half.
    #pragma unroll
    for (int mi = 0; mi < 2; ++mi) {
        #pragma unroll
        for (int ni = 0; ni < 2; ++ni) {
            int col = bn + wn + ni * 32 + l32;
            float bcol = bias[col];
            #pragma unroll
            for (int reg = 0; reg < 16; ++reg) {
                int row = bm + wm + mi * 32 + (reg & 3) + 8 * (reg >> 2) + 4 * half;
                float v = acc[mi][ni][reg] + bcol;
                if constexpr (EPI == 0) {
                    int sec = col >> 10, cc = col & 1023;
                    int head = cc >> 6, d = cc & 63;
                    int batch = row >> 11, tt = row & 2047;
                    size_t bh = (size_t)(batch * 16 + head);
                    if (sec == 0)   // Q pre-scaled by 0.125*log2(e) for exp2 softmax
                        ((unsigned short*)out0)[(bh * 2048 + tt) * 64 + d] =
                            f2bf(v * 0.18033688011112042f);
                    else if (sec == 1)
                        ((unsigned short*)out1)[(bh * 2048 + tt) * 64 + d] = f2bf(v);
                    else
                        ((unsigned short*)out2)[(bh * 64 + d) * 2048 + tt] = f2bf(v);
                } else if constexpr (EPI == 1) {
                    ((float*)out0)[(size_t)row * N + col] =
                        resid[(size_t)row * N + col] + v;
                } else {
                    // GELU(v) = v * sigmoid(2u), u = 0.79788456*(v+0.044715 v^3)
                    float u2 = 1.5957691216057308f * (v + 0.044715f * v * v * v);
                    float gl = v * __builtin_amdgcn_rcpf(1.0f + __expf(-u2));
                    ((unsigned short*)out0)[(size_t)row * N + col] = f2bf(gl);
                }
            }
        }
    }
}

// ---------------------------------------------------------------------------
// Flash attention (non-causal), S^T formulation.
// Q (pre-scaled by 0.125*log2e), K: [BH, T, 64] bf16.  Vt: [BH, 64, T] bf16.
// Block = 4 waves * 32 queries = 128 q; key tiles of 64.
// kf/vf hoisted across qt; no-max softmax with exp2; l via ones-MFMA.
// ---------------------------------------------------------------------------
__global__ __launch_bounds__(256, 3) void flash_attn(
    const unsigned short* __restrict__ Q, const unsigned short* __restrict__ Kk,
    const unsigned short* __restrict__ Vt, unsigned short* __restrict__ Y)
{
    __shared__ unsigned short Ks[64 * 64];      // [key][d], swizzled chunks
    __shared__ unsigned short Vs[64 * 64];      // [d][key], swizzled chunks
    __shared__ unsigned short Ps[4][16 * 72];   // per-wave P [q][key]
    const int bh = blockIdx.y;                  // 0..63
    const int batch = bh >> 4, head = bh & 15;
    const int t = threadIdx.x, w = t >> 6, lane = t & 63;
    const int lq = lane >> 4, lr = lane & 15;
    const int q0 = blockIdx.x * 128 + w * 32;   // wave's first query
    const size_t base = (size_t)bh * 2048 * 64;

    short8 qf[2][2];
    #pragma unroll
    for (int qt = 0; qt < 2; ++qt)
        #pragma unroll
        for (int c = 0; c < 2; ++c)
            qf[qt][c] = *(const short8*)
                &Q[base + (size_t)(q0 + qt * 16 + lr) * 64 + c * 32 + lq * 8];

    // Invariant staging offsets.
    int kg[2], vg[2], lo[2];
    #pragma unroll
    for (int c2 = 0; c2 < 2; ++c2) {
        int idx = t + c2 * 256;                 // 0..511
        int row = idx >> 3, ps = idx & 7;
        int p = (ps - row) & 7;
        kg[c2] = row * 64 + p * 8;
        vg[c2] = row * 2048 + p * 8;
        lo[c2] = idx * 8;
    }
    // Invariant fragment offsets.
    int kvo[4][2];
    #pragma unroll
    for (int i = 0; i < 4; ++i)
        #pragma unroll
        for (int c = 0; c < 2; ++c) {
            int row = i * 16 + lr;
            kvo[i][c] = row * 64 + (((c * 4 + lq + row) & 7) << 3);
        }
    const unsigned short* Kb = Kk + base;       // += 64*64 per tile (SGPR)
    const unsigned short* Vb = Vt + base;       // += 64 per tile (SGPR)

    short8 ones;
    #pragma unroll
    for (int i = 0; i < 8; ++i) ones[i] = (short)0x3F80;    // bf16 1.0

    fx4 lacc[2];
    fx4 o[2][4];                                // o[qt][dn]: O^T, row=d, col=q
    #pragma unroll
    for (int qt = 0; qt < 2; ++qt) {
        lacc[qt] = 0.0f;
        #pragma unroll
        for (int dn = 0; dn < 4; ++dn) o[qt][dn] = 0.0f;
    }

    for (int kt = 0; kt < 32; ++kt) {
        __syncthreads();                        // prev tile reads done
        #pragma unroll
        for (int c2 = 0; c2 < 2; ++c2) {
            ld_lds16(Kb + kg[c2], &Ks[lo[c2]]);
            ld_lds16(Vb + vg[c2], &Vs[lo[c2]]);
        }
        Kb += 64 * 64; Vb += 64;
        __syncthreads();                        // drains vmcnt(0)

        short8 kf[4][2], vf[4][2];
        #pragma unroll
        for (int kn = 0; kn < 4; ++kn)
            #pragma unroll
            for (int c = 0; c < 2; ++c)
                kf[kn][c] = *(const short8*)&Ks[kvo[kn][c]];
        #pragma unroll
        for (int dn = 0; dn < 4; ++dn)
            #pragma unroll
            for (int c = 0; c < 2; ++c)
                vf[dn][c] = *(const short8*)&Vs[kvo[dn][c]];

        #pragma unroll
        for (int qt = 0; qt < 2; ++qt) {
            #pragma unroll
            for (int kn = 0; kn < 4; ++kn) {
                fx4 s = 0.0f;
                s = __builtin_amdgcn_mfma_f32_16x16x32_bf16(
                    kf[kn][0], qf[qt][0], s, 0, 0, 0);
                s = __builtin_amdgcn_mfma_f32_16x16x32_bf16(
                    kf[kn][1], qf[qt][1], s, 0, 0, 0);
                float p0 = fexp2(s[0]);
                float p1 = fexp2(s[1]);
                float p2 = fexp2(s[2]);
                float p3 = fexp2(s[3]);
                uint2 pk;
                pk.x = pack_trunc(p0, p1);
                pk.y = pack_trunc(p2, p3);
                *(uint2*)&Ps[w][lr * 72 + kn * 16 + lq * 4] = pk;
            }
            short8 pf0 = *(const short8*)&Ps[w][lr * 72 + lq * 8];
            short8 pf1 = *(const short8*)&Ps[w][lr * 72 + 32 + lq * 8];
            lacc[qt] = __builtin_amdgcn_mfma_f32_16x16x32_bf16(
                ones, pf0, lacc[qt], 0, 0, 0);
            lacc[qt] = __builtin_amdgcn_mfma_f32_16x16x32_bf16(
                ones, pf1, lacc[qt], 0, 0, 0);
            #pragma unroll
            for (int dn = 0; dn < 4; ++dn) {
                o[qt][dn] = __builtin_amdgcn_mfma_f32_16x16x32_bf16(
                    vf[dn][0], pf0, o[qt][dn], 0, 0, 0);
                o[qt][dn] = __builtin_amdgcn_mfma_f32_16x16x32_bf16(
                    vf[dn][1], pf1, o[qt][dn], 0, 0, 0);
            }
        }
    }

    // Normalize (l in same col=q layout as o: no shuffles) and write Y[B,T,C].
    #pragma unroll
    for (int qt = 0; qt < 2; ++qt) {
        float inv = __builtin_amdgcn_rcpf(lacc[qt][0]);
        int qg = q0 + qt * 16 + lr;
        #pragma unroll
        for (int dn = 0; dn < 4; ++dn) {
            ushort4 ov;
            ov.x = f2bf(o[qt][dn][0] * inv);
            ov.y = f2bf(o[qt][dn][1] * inv);
            ov.z = f2bf(o[qt][dn][2] * inv);
            ov.w = f2bf(o[qt][dn][3] * inv);
            *(ushort4*)&Y[((size_t)(batch * 2048 + qg)) * 1024 +
                          head * 64 + dn * 16 + lq * 4] = ov;
        }
    }
}

// ---------------------------------------------------------------------------
extern "C" void kernel_launch(void* const* d_in, const int* in_sizes, int n_in,
                              void* d_out, int out_size, void* d_ws, size_t ws_size,
                              hipStream_t stream)
{
    const float* x      = (const float*)d_in[0];
    const float* ln1_g  = (const float*)d_in[1];
    const float* ln1_b  = (const float*)d_in[2];
    const float* w_qkv  = (const float*)d_in[3];
    const float* b_qkv  = (const float*)d_in[4];
    const float* w_ap   = (const float*)d_in[5];
    const float* b_ap   = (const float*)d_in[6];
    const float* ln2_g  = (const float*)d_in[7];
    const float* ln2_b  = (const float*)d_in[8];
    const float* w_fc   = (const float*)d_in[9];
    const float* b_fc   = (const float*)d_in[10];
    const float* w_proj = (const float*)d_in[11];
    const float* b_proj = (const float*)d_in[12];
    float* out = (float*)d_out;

    char* ws = (char*)d_ws;
    unsigned short* wT_qkv = (unsigned short*)(ws + 0);          // 3072x1024 bf16
    unsigned short* wT_ap  = (unsigned short*)(ws + 6291456);    // 1024x1024
    unsigned short* wT_fc  = (unsigned short*)(ws + 8388608);    // 4096x1024
    unsigned short* wT_pr  = (unsigned short*)(ws + 16777216);   // 1024x4096
    float*          x2     = (float*)(ws + 25165824);            // 8192x1024 f32
    unsigned short* Abuf   = (unsigned short*)(ws + 58720256);   // 8192x1024 bf16
    unsigned short* Qb     = (unsigned short*)(ws + 75497472);
    unsigned short* Kb     = (unsigned short*)(ws + 75497472 + 16777216);
    unsigned short* Vtb    = (unsigned short*)(ws + 75497472 + 33554432);
    unsigned short* H3     = (unsigned short*)(ws + 75497472);   // aliases Q/K/Vt

    transpose_all<<<12288, dim3(32, 8), 0, stream>>>(
        w_qkv, wT_qkv, w_ap, wT_ap, w_fc, wT_fc, w_proj, wT_pr);

    // LN1 -> h1 (bf16)
    layernorm_bf16<<<8192, 256, 0, stream>>>(x, ln1_g, ln1_b, Abuf);
    // QKV GEMM, scatter Q(scaled)/K/Vt
    gemm_bt<0><<<dim3(24, 64), 256, 0, stream>>>(Abuf, wT_qkv, b_qkv, nullptr,
                                                 Qb, Kb, Vtb, 8192, 3072, 1024);
    // attention -> Y (reuses Abuf)
    flash_attn<<<dim3(16, 64), 256, 0, stream>>>(Qb, Kb, Vtb, Abuf);
    // attn proj + residual -> x2 (f32)
    gemm_bt<1><<<dim3(8, 64), 256, 0, stream>>>(Abuf, wT_ap, b_ap, x,
                                                x2, nullptr, nullptr, 8192, 1024, 1024);
    // LN2 -> h2 (bf16, reuses Abuf)
    layernorm_bf16<<<8192, 256, 0, stream>>>(x2, ln2_g, ln2_b, Abuf);
    // FC + GELU -> h3 (bf16, aliases Q/K/Vt region)
    gemm_bt<2><<<dim3(32, 64), 256, 0, stream>>>(Abuf, wT_fc, b_fc, nullptr,
                                                 H3, nullptr, nullptr, 8192, 4096, 1024);
    // proj + residual -> out (f32)
    gemm_bt<1><<<dim3(8, 64), 256, 0, stream>>>(H3, wT_pr, b_proj, x2,
                                                out, nullptr, nullptr, 8192, 1024, 4096);
}

// Round 8
// 529.535 us; speedup vs baseline: 1.3218x; 1.3218x over previous
//
#include <hip/hip_runtime.h>

// ---------------------------------------------------------------------------
// Transformer block, B=4 T=2048 C=1024 H=16 hd=64 DFF=4096, bf16 MFMA compute.
// R8: revert R7 (direct-B regression). R6 structure + __launch_bounds__(256,3)
// on gemm_bt: cap total regs ~170 (incl 64 AGPR acc) -> 3 blocks/CU.
// ---------------------------------------------------------------------------

typedef __attribute__((ext_vector_type(8))) short short8;   // 8 bf16 = 4 VGPRs
typedef __attribute__((ext_vector_type(4))) float fx4;      // 16x16 MFMA acc
typedef __attribute__((ext_vector_type(16))) float fx16;    // 32x32 MFMA acc

__device__ __forceinline__ unsigned short f2bf(float f) {
    union { float f; unsigned u; } v; v.f = f;
    unsigned r = v.u + 0x7fffu + ((v.u >> 16) & 1u);  // RNE
    return (unsigned short)(r >> 16);
}

__device__ __forceinline__ float fexp2(float x) {
#if __has_builtin(__builtin_amdgcn_exp2f)
    return __builtin_amdgcn_exp2f(x);
#else
    return __expf(x * 0.69314718055994531f);
#endif
}

// pack two f32 -> two bf16 (truncation) in one v_perm_b32
__device__ __forceinline__ unsigned pack_trunc(float lo, float hi) {
    return __builtin_amdgcn_perm(__float_as_uint(hi), __float_as_uint(lo),
                                 0x07060302u);
}

// async global->LDS, 16B per lane; LDS dest = wave-uniform base + lane*16
__device__ __forceinline__ void ld_lds16(const void* g, void* l) {
    __builtin_amdgcn_global_load_lds(
        (const __attribute__((address_space(1))) unsigned int*)g,
        (__attribute__((address_space(3))) unsigned int*)l, 16, 0, 0);
}

// ---------------------------------------------------------------------------
// All four weight transposes in one launch. in [R][Cn] f32 -> out [Cn][R] bf16
// ---------------------------------------------------------------------------
__global__ __launch_bounds__(256) void transpose_all(
    const float* __restrict__ w0, unsigned short* __restrict__ o0,
    const float* __restrict__ w1, unsigned short* __restrict__ o1,
    const float* __restrict__ w2, unsigned short* __restrict__ o2,
    const float* __restrict__ w3, unsigned short* __restrict__ o3)
{
    __shared__ float tile[32][33];
    int b = blockIdx.x;
    const float* in; unsigned short* out; int R, Cn;
    if (b < 3072)      { in = w0; out = o0; R = 1024; Cn = 3072; }
    else if (b < 4096) { b -= 3072; in = w1; out = o1; R = 1024; Cn = 1024; }
    else if (b < 8192) { b -= 4096; in = w2; out = o2; R = 1024; Cn = 4096; }
    else               { b -= 8192; in = w3; out = o3; R = 4096; Cn = 1024; }
    int tilesX = Cn >> 5;
    int c0 = (b % tilesX) * 32, r0 = (b / tilesX) * 32;
    int tx = threadIdx.x, ty = threadIdx.y;                 // block (32,8)
    for (int i = 0; i < 4; ++i)
        tile[ty + i * 8][tx] = in[(size_t)(r0 + ty + i * 8) * Cn + c0 + tx];
    __syncthreads();
    for (int i = 0; i < 4; ++i)
        out[(size_t)(c0 + ty + i * 8) * R + r0 + tx] = f2bf(tile[tx][ty + i * 8]);
}

// ---------------------------------------------------------------------------
// LayerNorm row kernel: fp32 in -> bf16 out.  C = 1024, block = 256.
// ---------------------------------------------------------------------------
__global__ __launch_bounds__(256) void layernorm_bf16(
    const float* __restrict__ x, const float* __restrict__ g,
    const float* __restrict__ bb, unsigned short* __restrict__ out)
{
    const int C = 1024;
    int row = blockIdx.x;
    const float* xr = x + (size_t)row * C;
    float4 v = ((const float4*)xr)[threadIdx.x];
    float s  = v.x + v.y + v.z + v.w;
    float ss = v.x * v.x + v.y * v.y + v.z * v.z + v.w * v.w;
    for (int off = 32; off >= 1; off >>= 1) {
        s  += __shfl_xor(s,  off);
        ss += __shfl_xor(ss, off);
    }
    __shared__ float sbuf[2][4];
    int wave = threadIdx.x >> 6;
    if ((threadIdx.x & 63) == 0) { sbuf[0][wave] = s; sbuf[1][wave] = ss; }
    __syncthreads();
    s  = sbuf[0][0] + sbuf[0][1] + sbuf[0][2] + sbuf[0][3];
    ss = sbuf[1][0] + sbuf[1][1] + sbuf[1][2] + sbuf[1][3];
    float mu   = s * (1.0f / C);
    float var  = ss * (1.0f / C) - mu * mu;
    float rstd = rsqrtf(var + 1e-5f);
    int i = threadIdx.x * 4;
    ushort4 o;
    o.x = f2bf((v.x - mu) * rstd * g[i + 0] + bb[i + 0]);
    o.y = f2bf((v.y - mu) * rstd * g[i + 1] + bb[i + 1]);
    o.z = f2bf((v.z - mu) * rstd * g[i + 2] + bb[i + 2]);
    o.w = f2bf((v.w - mu) * rstd * g[i + 3] + bb[i + 3]);
    ((ushort4*)(out + (size_t)row * C))[threadIdx.x] = o;
}

// ---------------------------------------------------------------------------
// Generic bf16 GEMM, C = A[M,K] @ B[K,N] with B given transposed (Bt[N,K]).
// 128x128 tile, BK=64, saddr-form global_load_lds staging, swizzled LDS
// slot=(chunk+row)&7. Inner: mfma_f32_32x32x16_bf16, 2x2 tiles per wave.
// __launch_bounds__(256,3): cap total regs (arch+AGPR) ~170 -> 3 blocks/CU.
// C/D: col=lane&31, row=(reg&3)+8*(reg>>2)+4*(lane>>5)  [m74/m101 verified].
// EPI 0: +bias, scatter to Q*scl[BH,T,64] / K[BH,T,64] / Vt[BH,64,T] (bf16)
// EPI 1: +bias +resid(f32) -> f32 out
// EPI 2: +bias, GELU -> bf16 out
// ---------------------------------------------------------------------------
template <int EPI>
__global__ __launch_bounds__(256, 3) void gemm_bt(
    const unsigned short* __restrict__ A, const unsigned short* __restrict__ Bt,
    const float* __restrict__ bias, const float* __restrict__ resid,
    void* __restrict__ out0, void* __restrict__ out1, void* __restrict__ out2,
    int M, int N, int K)
{
    __shared__ unsigned short As[128 * 64];
    __shared__ unsigned short Bs[128 * 64];
    const int bm = blockIdx.y * 128, bn = blockIdx.x * 128;
    const int t = threadIdx.x, wave = t >> 6, lane = t & 63;
    const int wm = (wave >> 1) * 64, wn = (wave & 1) * 64;
    const int l32 = lane & 31, half = lane >> 5;

    // Loop-invariant staging offsets (elements) and LDS slots.
    int goff[4], loff[4];
    #pragma unroll
    for (int c = 0; c < 4; ++c) {
        int idx = t + c * 256;                // 0..1023, 16B per slot
        int row = idx >> 3, ps = idx & 7;
        int p = (ps - row) & 7;               // global chunk held at slot ps
        goff[c] = row * K + p * 8;
        loff[c] = idx * 8;
    }
    // Loop-invariant fragment LDS offsets: [tile][kstep]
    int aoffs[2][4], boffs[2][4];
    #pragma unroll
    for (int i = 0; i < 2; ++i)
        #pragma unroll
        for (int s = 0; s < 4; ++s) {
            int ra = wm + i * 32 + l32;
            int rb = wn + i * 32 + l32;
            aoffs[i][s] = ra * 64 + (((s * 2 + half + ra) & 7) << 3);
            boffs[i][s] = rb * 64 + (((s * 2 + half + rb) & 7) << 3);
        }

    const unsigned short* Ab = A + (size_t)bm * K;   // advances 64/iter (SGPR)
    const unsigned short* Bb = Bt + (size_t)bn * K;

    fx16 acc[2][2];
    #pragma unroll
    for (int mi = 0; mi < 2; ++mi)
        #pragma unroll
        for (int ni = 0; ni < 2; ++ni)
            acc[mi][ni] = 0.0f;

    for (int it = 0, nit = K >> 6; it < nit; ++it) {
        #pragma unroll
        for (int c = 0; c < 4; ++c) {
            ld_lds16(Ab + goff[c], &As[loff[c]]);
            ld_lds16(Bb + goff[c], &Bs[loff[c]]);
        }
        Ab += 64; Bb += 64;
        __syncthreads();                      // drains vmcnt(0)
        #pragma unroll
        for (int s = 0; s < 4; ++s) {
            short8 a0 = *(const short8*)&As[aoffs[0][s]];
            short8 a1 = *(const short8*)&As[aoffs[1][s]];
            short8 b0 = *(const short8*)&Bs[boffs[0][s]];
            short8 b1 = *(const short8*)&Bs[boffs[1][s]];
            acc[0][0] = __builtin_amdgcn_mfma_f32_32x32x16_bf16(a0, b0, acc[0][0], 0, 0, 0);
            acc[0][1] = __builtin_amdgcn_mfma_f32_32x32x16_bf16(a0, b1, acc[0][1], 0, 0, 0);
            acc[1][0] = __builtin_amdgcn_mfma_f32_32x32x16_bf16(a1, b0, acc[1][0], 0, 0, 0);
            acc[1][1] = __builtin_amdgcn_mfma_f32_32x32x16_bf16(a1, b1, acc[1][1], 0, 0, 0);
        }
        __syncthreads();
    }

    // Epilogue. C/D: col=lane&31, row=(reg&3)+8*(reg>>2)+4*half.
    #pragma unroll
    for (int mi = 0; mi < 2; ++mi) {
        #pragma unroll
        for (int ni = 0; ni < 2; ++ni) {
            int col = bn + wn + ni * 32 + l32;
            float bcol = bias[col];
            #pragma unroll
            for (int reg = 0; reg < 16; ++reg) {
                int row = bm + wm + mi * 32 + (reg & 3) + 8 * (reg >> 2) + 4 * half;
                float v = acc[mi][ni][reg] + bcol;
                if constexpr (EPI == 0) {
                    int sec = col >> 10, cc = col & 1023;
                    int head = cc >> 6, d = cc & 63;
                    int batch = row >> 11, tt = row & 2047;
                    size_t bh = (size_t)(batch * 16 + head);
                    if (sec == 0)   // Q pre-scaled by 0.125*log2(e) for exp2 softmax
                        ((unsigned short*)out0)[(bh * 2048 + tt) * 64 + d] =
                            f2bf(v * 0.18033688011112042f);
                    else if (sec == 1)
                        ((unsigned short*)out1)[(bh * 2048 + tt) * 64 + d] = f2bf(v);
                    else
                        ((unsigned short*)out2)[(bh * 64 + d) * 2048 + tt] = f2bf(v);
                } else if constexpr (EPI == 1) {
                    ((float*)out0)[(size_t)row * N + col] =
                        resid[(size_t)row * N + col] + v;
                } else {
                    // GELU(v) = v * sigmoid(2u), u = 0.79788456*(v+0.044715 v^3)
                    float u2 = 1.5957691216057308f * (v + 0.044715f * v * v * v);
                    float gl = v * __builtin_amdgcn_rcpf(1.0f + __expf(-u2));
                    ((unsigned short*)out0)[(size_t)row * N + col] = f2bf(gl);
                }
            }
        }
    }
}

// ---------------------------------------------------------------------------
// Flash attention (non-causal), S^T formulation.
// Q (pre-scaled by 0.125*log2e), K: [BH, T, 64] bf16.  Vt: [BH, 64, T] bf16.
// Block = 4 waves * 32 queries = 128 q; key tiles of 64.
// kf/vf hoisted across qt; no-max softmax with exp2; l via ones-MFMA.
// ---------------------------------------------------------------------------
__global__ __launch_bounds__(256, 3) void flash_attn(
    const unsigned short* __restrict__ Q, const unsigned short* __restrict__ Kk,
    const unsigned short* __restrict__ Vt, unsigned short* __restrict__ Y)
{
    __shared__ unsigned short Ks[64 * 64];      // [key][d], swizzled chunks
    __shared__ unsigned short Vs[64 * 64];      // [d][key], swizzled chunks
    __shared__ unsigned short Ps[4][16 * 72];   // per-wave P [q][key]
    const int bh = blockIdx.y;                  // 0..63
    const int batch = bh >> 4, head = bh & 15;
    const int t = threadIdx.x, w = t >> 6, lane = t & 63;
    const int lq = lane >> 4, lr = lane & 15;
    const int q0 = blockIdx.x * 128 + w * 32;   // wave's first query
    const size_t base = (size_t)bh * 2048 * 64;

    short8 qf[2][2];
    #pragma unroll
    for (int qt = 0; qt < 2; ++qt)
        #pragma unroll
        for (int c = 0; c < 2; ++c)
            qf[qt][c] = *(const short8*)
                &Q[base + (size_t)(q0 + qt * 16 + lr) * 64 + c * 32 + lq * 8];

    // Invariant staging offsets.
    int kg[2], vg[2], lo[2];
    #pragma unroll
    for (int c2 = 0; c2 < 2; ++c2) {
        int idx = t + c2 * 256;                 // 0..511
        int row = idx >> 3, ps = idx & 7;
        int p = (ps - row) & 7;
        kg[c2] = row * 64 + p * 8;
        vg[c2] = row * 2048 + p * 8;
        lo[c2] = idx * 8;
    }
    // Invariant fragment offsets.
    int kvo[4][2];
    #pragma unroll
    for (int i = 0; i < 4; ++i)
        #pragma unroll
        for (int c = 0; c < 2; ++c) {
            int row = i * 16 + lr;
            kvo[i][c] = row * 64 + (((c * 4 + lq + row) & 7) << 3);
        }
    const unsigned short* Kb = Kk + base;       // += 64*64 per tile (SGPR)
    const unsigned short* Vb = Vt + base;       // += 64 per tile (SGPR)

    short8 ones;
    #pragma unroll
    for (int i = 0; i < 8; ++i) ones[i] = (short)0x3F80;    // bf16 1.0

    fx4 lacc[2];
    fx4 o[2][4];                                // o[qt][dn]: O^T, row=d, col=q
    #pragma unroll
    for (int qt = 0; qt < 2; ++qt) {
        lacc[qt] = 0.0f;
        #pragma unroll
        for (int dn = 0; dn < 4; ++dn) o[qt][dn] = 0.0f;
    }

    for (int kt = 0; kt < 32; ++kt) {
        __syncthreads();                        // prev tile reads done
        #pragma unroll
        for (int c2 = 0; c2 < 2; ++c2) {
            ld_lds16(Kb + kg[c2], &Ks[lo[c2]]);
            ld_lds16(Vb + vg[c2], &Vs[lo[c2]]);
        }
        Kb += 64 * 64; Vb += 64;
        __syncthreads();                        // drains vmcnt(0)

        short8 kf[4][2], vf[4][2];
        #pragma unroll
        for (int kn = 0; kn < 4; ++kn)
            #pragma unroll
            for (int c = 0; c < 2; ++c)
                kf[kn][c] = *(const short8*)&Ks[kvo[kn][c]];
        #pragma unroll
        for (int dn = 0; dn < 4; ++dn)
            #pragma unroll
            for (int c = 0; c < 2; ++c)
                vf[dn][c] = *(const short8*)&Vs[kvo[dn][c]];

        #pragma unroll
        for (int qt = 0; qt < 2; ++qt) {
            #pragma unroll
            for (int kn = 0; kn < 4; ++kn) {
                fx4 s = 0.0f;
                s = __builtin_amdgcn_mfma_f32_16x16x32_bf16(
                    kf[kn][0], qf[qt][0], s, 0, 0, 0);
                s = __builtin_amdgcn_mfma_f32_16x16x32_bf16(
                    kf[kn][1], qf[qt][1], s, 0, 0, 0);
                float p0 = fexp2(s[0]);
                float p1 = fexp2(s[1]);
                float p2 = fexp2(s[2]);
                float p3 = fexp2(s[3]);
                uint2 pk;
                pk.x = pack_trunc(p0, p1);
                pk.y = pack_trunc(p2, p3);
                *(uint2*)&Ps[w][lr * 72 + kn * 16 + lq * 4] = pk;
            }
            short8 pf0 = *(const short8*)&Ps[w][lr * 72 + lq * 8];
            short8 pf1 = *(const short8*)&Ps[w][lr * 72 + 32 + lq * 8];
            lacc[qt] = __builtin_amdgcn_mfma_f32_16x16x32_bf16(
                ones, pf0, lacc[qt], 0, 0, 0);
            lacc[qt] = __builtin_amdgcn_mfma_f32_16x16x32_bf16(
                ones, pf1, lacc[qt], 0, 0, 0);
            #pragma unroll
            for (int dn = 0; dn < 4; ++dn) {
                o[qt][dn] = __builtin_amdgcn_mfma_f32_16x16x32_bf16(
                    vf[dn][0], pf0, o[qt][dn], 0, 0, 0);
                o[qt][dn] = __builtin_amdgcn_mfma_f32_16x16x32_bf16(
                    vf[dn][1], pf1, o[qt][dn], 0, 0, 0);
            }
        }
    }

    // Normalize (l in same col=q layout as o: no shuffles) and write Y[B,T,C].
    #pragma unroll
    for (int qt = 0; qt < 2; ++qt) {
        float inv = __builtin_amdgcn_rcpf(lacc[qt][0]);
        int qg = q0 + qt * 16 + lr;
        #pragma unroll
        for (int dn = 0; dn < 4; ++dn) {
            ushort4 ov;
            ov.x = f2bf(o[qt][dn][0] * inv);
            ov.y = f2bf(o[qt][dn][1] * inv);
            ov.z = f2bf(o[qt][dn][2] * inv);
            ov.w = f2bf(o[qt][dn][3] * inv);
            *(ushort4*)&Y[((size_t)(batch * 2048 + qg)) * 1024 +
                          head * 64 + dn * 16 + lq * 4] = ov;
        }
    }
}

// ---------------------------------------------------------------------------
extern "C" void kernel_launch(void* const* d_in, const int* in_sizes, int n_in,
                              void* d_out, int out_size, void* d_ws, size_t ws_size,
                              hipStream_t stream)
{
    const float* x      = (const float*)d_in[0];
    const float* ln1_g  = (const float*)d_in[1];
    const float* ln1_b  = (const float*)d_in[2];
    const float* w_qkv  = (const float*)d_in[3];
    const float* b_qkv  = (const float*)d_in[4];
    const float* w_ap   = (const float*)d_in[5];
    const float* b_ap   = (const float*)d_in[6];
    const float* ln2_g  = (const float*)d_in[7];
    const float* ln2_b  = (const float*)d_in[8];
    const float* w_fc   = (const float*)d_in[9];
    const float* b_fc   = (const float*)d_in[10];
    const float* w_proj = (const float*)d_in[11];
    const float* b_proj = (const float*)d_in[12];
    float* out = (float*)d_out;

    char* ws = (char*)d_ws;
    unsigned short* wT_qkv = (unsigned short*)(ws + 0);          // 3072x1024 bf16
    unsigned short* wT_ap  = (unsigned short*)(ws + 6291456);    // 1024x1024
    unsigned short* wT_fc  = (unsigned short*)(ws + 8388608);    // 4096x1024
    unsigned short* wT_pr  = (unsigned short*)(ws + 16777216);   // 1024x4096
    float*          x2     = (float*)(ws + 25165824);            // 8192x1024 f32
    unsigned short* Abuf   = (unsigned short*)(ws + 58720256);   // 8192x1024 bf16
    unsigned short* Qb     = (unsigned short*)(ws + 75497472);
    unsigned short* Kb     = (unsigned short*)(ws + 75497472 + 16777216);
    unsigned short* Vtb    = (unsigned short*)(ws + 75497472 + 33554432);
    unsigned short* H3     = (unsigned short*)(ws + 75497472);   // aliases Q/K/Vt

    transpose_all<<<12288, dim3(32, 8), 0, stream>>>(
        w_qkv, wT_qkv, w_ap, wT_ap, w_fc, wT_fc, w_proj, wT_pr);

    // LN1 -> h1 (bf16)
    layernorm_bf16<<<8192, 256, 0, stream>>>(x, ln1_g, ln1_b, Abuf);
    // QKV GEMM, scatter Q(scaled)/K/Vt
    gemm_bt<0><<<dim3(24, 64), 256, 0, stream>>>(Abuf, wT_qkv, b_qkv, nullptr,
                                                 Qb, Kb, Vtb, 8192, 3072, 1024);
    // attention -> Y (reuses Abuf)
    flash_attn<<<dim3(16, 64), 256, 0, stream>>>(Qb, Kb, Vtb, Abuf);
    // attn proj + residual -> x2 (f32)
    gemm_bt<1><<<dim3(8, 64), 256, 0, stream>>>(Abuf, wT_ap, b_ap, x,
                                                x2, nullptr, nullptr, 8192, 1024, 1024);
    // LN2 -> h2 (bf16, reuses Abuf)
    layernorm_bf16<<<8192, 256, 0, stream>>>(x2, ln2_g, ln2_b, Abuf);
    // FC + GELU -> h3 (bf16, aliases Q/K/Vt region)
    gemm_bt<2><<<dim3(32, 64), 256, 0, stream>>>(Abuf, wT_fc, b_fc, nullptr,
                                                 H3, nullptr, nullptr, 8192, 4096, 1024);
    // proj + residual -> out (f32)
    gemm_bt<1><<<dim3(8, 64), 256, 0, stream>>>(H3, wT_pr, b_proj, x2,
                                                out, nullptr, nullptr, 8192, 1024, 4096);
}

// Round 9
// 510.289 us; speedup vs baseline: 1.3716x; 1.0377x over previous
//
#include <hip/hip_runtime.h>

// ---------------------------------------------------------------------------
// Transformer block, B=4 T=2048 C=1024 H=16 hd=64 DFF=4096, bf16 MFMA compute.
// R9: revert R8's reg cap (it cost 3%). GEMMs = R6 config (best, ~750 TF).
// proj & attn-proj (K=4096): column-major block order -> blocks sharing an
// A-row-panel get identical pid%8 -> same XCD L2 (A is the 64MB re-read).
// ---------------------------------------------------------------------------

typedef __attribute__((ext_vector_type(8))) short short8;   // 8 bf16 = 4 VGPRs
typedef __attribute__((ext_vector_type(4))) float fx4;      // 16x16 MFMA acc
typedef __attribute__((ext_vector_type(16))) float fx16;    // 32x32 MFMA acc

__device__ __forceinline__ unsigned short f2bf(float f) {
    union { float f; unsigned u; } v; v.f = f;
    unsigned r = v.u + 0x7fffu + ((v.u >> 16) & 1u);  // RNE
    return (unsigned short)(r >> 16);
}

__device__ __forceinline__ float fexp2(float x) {
#if __has_builtin(__builtin_amdgcn_exp2f)
    return __builtin_amdgcn_exp2f(x);
#else
    return __expf(x * 0.69314718055994531f);
#endif
}

// pack two f32 -> two bf16 (truncation) in one v_perm_b32
__device__ __forceinline__ unsigned pack_trunc(float lo, float hi) {
    return __builtin_amdgcn_perm(__float_as_uint(hi), __float_as_uint(lo),
                                 0x07060302u);
}

// async global->LDS, 16B per lane; LDS dest = wave-uniform base + lane*16
__device__ __forceinline__ void ld_lds16(const void* g, void* l) {
    __builtin_amdgcn_global_load_lds(
        (const __attribute__((address_space(1))) unsigned int*)g,
        (__attribute__((address_space(3))) unsigned int*)l, 16, 0, 0);
}

// ---------------------------------------------------------------------------
// All four weight transposes in one launch. in [R][Cn] f32 -> out [Cn][R] bf16
// ---------------------------------------------------------------------------
__global__ __launch_bounds__(256) void transpose_all(
    const float* __restrict__ w0, unsigned short* __restrict__ o0,
    const float* __restrict__ w1, unsigned short* __restrict__ o1,
    const float* __restrict__ w2, unsigned short* __restrict__ o2,
    const float* __restrict__ w3, unsigned short* __restrict__ o3)
{
    __shared__ float tile[32][33];
    int b = blockIdx.x;
    const float* in; unsigned short* out; int R, Cn;
    if (b < 3072)      { in = w0; out = o0; R = 1024; Cn = 3072; }
    else if (b < 4096) { b -= 3072; in = w1; out = o1; R = 1024; Cn = 1024; }
    else if (b < 8192) { b -= 4096; in = w2; out = o2; R = 1024; Cn = 4096; }
    else               { b -= 8192; in = w3; out = o3; R = 4096; Cn = 1024; }
    int tilesX = Cn >> 5;
    int c0 = (b % tilesX) * 32, r0 = (b / tilesX) * 32;
    int tx = threadIdx.x, ty = threadIdx.y;                 // block (32,8)
    for (int i = 0; i < 4; ++i)
        tile[ty + i * 8][tx] = in[(size_t)(r0 + ty + i * 8) * Cn + c0 + tx];
    __syncthreads();
    for (int i = 0; i < 4; ++i)
        out[(size_t)(c0 + ty + i * 8) * R + r0 + tx] = f2bf(tile[tx][ty + i * 8]);
}

// ---------------------------------------------------------------------------
// LayerNorm row kernel: fp32 in -> bf16 out.  C = 1024, block = 256.
// ---------------------------------------------------------------------------
__global__ __launch_bounds__(256) void layernorm_bf16(
    const float* __restrict__ x, const float* __restrict__ g,
    const float* __restrict__ bb, unsigned short* __restrict__ out)
{
    const int C = 1024;
    int row = blockIdx.x;
    const float* xr = x + (size_t)row * C;
    float4 v = ((const float4*)xr)[threadIdx.x];
    float s  = v.x + v.y + v.z + v.w;
    float ss = v.x * v.x + v.y * v.y + v.z * v.z + v.w * v.w;
    for (int off = 32; off >= 1; off >>= 1) {
        s  += __shfl_xor(s,  off);
        ss += __shfl_xor(ss, off);
    }
    __shared__ float sbuf[2][4];
    int wave = threadIdx.x >> 6;
    if ((threadIdx.x & 63) == 0) { sbuf[0][wave] = s; sbuf[1][wave] = ss; }
    __syncthreads();
    s  = sbuf[0][0] + sbuf[0][1] + sbuf[0][2] + sbuf[0][3];
    ss = sbuf[1][0] + sbuf[1][1] + sbuf[1][2] + sbuf[1][3];
    float mu   = s * (1.0f / C);
    float var  = ss * (1.0f / C) - mu * mu;
    float rstd = rsqrtf(var + 1e-5f);
    int i = threadIdx.x * 4;
    ushort4 o;
    o.x = f2bf((v.x - mu) * rstd * g[i + 0] + bb[i + 0]);
    o.y = f2bf((v.y - mu) * rstd * g[i + 1] + bb[i + 1]);
    o.z = f2bf((v.z - mu) * rstd * g[i + 2] + bb[i + 2]);
    o.w = f2bf((v.w - mu) * rstd * g[i + 3] + bb[i + 3]);
    ((ushort4*)(out + (size_t)row * C))[threadIdx.x] = o;
}

// ---------------------------------------------------------------------------
// Generic bf16 GEMM, C = A[M,K] @ B[K,N] with B given transposed (Bt[N,K]).
// 128x128 tile, BK=64, saddr-form global_load_lds staging, swizzled LDS
// slot=(chunk+row)&7. Inner: mfma_f32_32x32x16_bf16, 2x2 tiles per wave.
// SWAP=true: grid is (gy, gx) and roles swap -> column-major block order
// (pid%8 = by%8 -> A-row-panel blocks co-located on one XCD).
// C/D: col=lane&31, row=(reg&3)+8*(reg>>2)+4*(lane>>5)  [m74/m101 verified].
// EPI 0: +bias, scatter to Q*scl[BH,T,64] / K[BH,T,64] / Vt[BH,64,T] (bf16)
// EPI 1: +bias +resid(f32) -> f32 out
// EPI 2: +bias, GELU -> bf16 out
// ---------------------------------------------------------------------------
template <int EPI, bool SWAP>
__global__ __launch_bounds__(256) void gemm_bt(
    const unsigned short* __restrict__ A, const unsigned short* __restrict__ Bt,
    const float* __restrict__ bias, const float* __restrict__ resid,
    void* __restrict__ out0, void* __restrict__ out1, void* __restrict__ out2,
    int M, int N, int K)
{
    __shared__ unsigned short As[128 * 64];
    __shared__ unsigned short Bs[128 * 64];
    const int bm = (SWAP ? blockIdx.x : blockIdx.y) * 128;
    const int bn = (SWAP ? blockIdx.y : blockIdx.x) * 128;
    const int t = threadIdx.x, wave = t >> 6, lane = t & 63;
    const int wm = (wave >> 1) * 64, wn = (wave & 1) * 64;
    const int l32 = lane & 31, half = lane >> 5;

    // Loop-invariant staging offsets (elements) and LDS slots.
    int goff[4], loff[4];
    #pragma unroll
    for (int c = 0; c < 4; ++c) {
        int idx = t + c * 256;                // 0..1023, 16B per slot
        int row = idx >> 3, ps = idx & 7;
        int p = (ps - row) & 7;               // global chunk held at slot ps
        goff[c] = row * K + p * 8;
        loff[c] = idx * 8;
    }
    // Loop-invariant fragment LDS offsets: [tile][kstep]
    int aoffs[2][4], boffs[2][4];
    #pragma unroll
    for (int i = 0; i < 2; ++i)
        #pragma unroll
        for (int s = 0; s < 4; ++s) {
            int ra = wm + i * 32 + l32;
            int rb = wn + i * 32 + l32;
            aoffs[i][s] = ra * 64 + (((s * 2 + half + ra) & 7) << 3);
            boffs[i][s] = rb * 64 + (((s * 2 + half + rb) & 7) << 3);
        }

    const unsigned short* Ab = A + (size_t)bm * K;   // advances 64/iter (SGPR)
    const unsigned short* Bb = Bt + (size_t)bn * K;

    fx16 acc[2][2];
    #pragma unroll
    for (int mi = 0; mi < 2; ++mi)
        #pragma unroll
        for (int ni = 0; ni < 2; ++ni)
            acc[mi][ni] = 0.0f;

    for (int it = 0, nit = K >> 6; it < nit; ++it) {
        #pragma unroll
        for (int c = 0; c < 4; ++c) {
            ld_lds16(Ab + goff[c], &As[loff[c]]);
            ld_lds16(Bb + goff[c], &Bs[loff[c]]);
        }
        Ab += 64; Bb += 64;
        __syncthreads();                      // drains vmcnt(0)
        #pragma unroll
        for (int s = 0; s < 4; ++s) {
            short8 a0 = *(const short8*)&As[aoffs[0][s]];
            short8 a1 = *(const short8*)&As[aoffs[1][s]];
            short8 b0 = *(const short8*)&Bs[boffs[0][s]];
            short8 b1 = *(const short8*)&Bs[boffs[1][s]];
            acc[0][0] = __builtin_amdgcn_mfma_f32_32x32x16_bf16(a0, b0, acc[0][0], 0, 0, 0);
            acc[0][1] = __builtin_amdgcn_mfma_f32_32x32x16_bf16(a0, b1, acc[0][1], 0, 0, 0);
            acc[1][0] = __builtin_amdgcn_mfma_f32_32x32x16_bf16(a1, b0, acc[1][0], 0, 0, 0);
            acc[1][1] = __builtin_amdgcn_mfma_f32_32x32x16_bf16(a1, b1, acc[1][1], 0, 0, 0);
        }
        __syncthreads();
    }

    // Epilogue. C/D: col=lane&31, row=(reg&3)+8*(reg>>2)+4*half.
    #pragma unroll
    for (int mi = 0; mi < 2; ++mi) {
        #pragma unroll
        for (int ni = 0; ni < 2; ++ni) {
            int col = bn + wn + ni * 32 + l32;
            float bcol = bias[col];
            #pragma unroll
            for (int reg = 0; reg < 16; ++reg) {
                int row = bm + wm + mi * 32 + (reg & 3) + 8 * (reg >> 2) + 4 * half;
                float v = acc[mi][ni][reg] + bcol;
                if constexpr (EPI == 0) {
                    int sec = col >> 10, cc = col & 1023;
                    int head = cc >> 6, d = cc & 63;
                    int batch = row >> 11, tt = row & 2047;
                    size_t bh = (size_t)(batch * 16 + head);
                    if (sec == 0)   // Q pre-scaled by 0.125*log2(e) for exp2 softmax
                        ((unsigned short*)out0)[(bh * 2048 + tt) * 64 + d] =
                            f2bf(v * 0.18033688011112042f);
                    else if (sec == 1)
                        ((unsigned short*)out1)[(bh * 2048 + tt) * 64 + d] = f2bf(v);
                    else
                        ((unsigned short*)out2)[(bh * 64 + d) * 2048 + tt] = f2bf(v);
                } else if constexpr (EPI == 1) {
                    ((float*)out0)[(size_t)row * N + col] =
                        resid[(size_t)row * N + col] + v;
                } else {
                    // GELU(v) = v * sigmoid(2u), u = 0.79788456*(v+0.044715 v^3)
                    float u2 = 1.5957691216057308f * (v + 0.044715f * v * v * v);
                    float gl = v * __builtin_amdgcn_rcpf(1.0f + __expf(-u2));
                    ((unsigned short*)out0)[(size_t)row * N + col] = f2bf(gl);
                }
            }
        }
    }
}

// ---------------------------------------------------------------------------
// Flash attention (non-causal), S^T formulation.
// Q (pre-scaled by 0.125*log2e), K: [BH, T, 64] bf16.  Vt: [BH, 64, T] bf16.
// Block = 4 waves * 32 queries = 128 q; key tiles of 64.
// kf/vf hoisted across qt; no-max softmax with exp2; l via ones-MFMA.
// ---------------------------------------------------------------------------
__global__ __launch_bounds__(256, 3) void flash_attn(
    const unsigned short* __restrict__ Q, const unsigned short* __restrict__ Kk,
    const unsigned short* __restrict__ Vt, unsigned short* __restrict__ Y)
{
    __shared__ unsigned short Ks[64 * 64];      // [key][d], swizzled chunks
    __shared__ unsigned short Vs[64 * 64];      // [d][key], swizzled chunks
    __shared__ unsigned short Ps[4][16 * 72];   // per-wave P [q][key]
    const int bh = blockIdx.y;                  // 0..63
    const int batch = bh >> 4, head = bh & 15;
    const int t = threadIdx.x, w = t >> 6, lane = t & 63;
    const int lq = lane >> 4, lr = lane & 15;
    const int q0 = blockIdx.x * 128 + w * 32;   // wave's first query
    const size_t base = (size_t)bh * 2048 * 64;

    short8 qf[2][2];
    #pragma unroll
    for (int qt = 0; qt < 2; ++qt)
        #pragma unroll
        for (int c = 0; c < 2; ++c)
            qf[qt][c] = *(const short8*)
                &Q[base + (size_t)(q0 + qt * 16 + lr) * 64 + c * 32 + lq * 8];

    // Invariant staging offsets.
    int kg[2], vg[2], lo[2];
    #pragma unroll
    for (int c2 = 0; c2 < 2; ++c2) {
        int idx = t + c2 * 256;                 // 0..511
        int row = idx >> 3, ps = idx & 7;
        int p = (ps - row) & 7;
        kg[c2] = row * 64 + p * 8;
        vg[c2] = row * 2048 + p * 8;
        lo[c2] = idx * 8;
    }
    // Invariant fragment offsets.
    int kvo[4][2];
    #pragma unroll
    for (int i = 0; i < 4; ++i)
        #pragma unroll
        for (int c = 0; c < 2; ++c) {
            int row = i * 16 + lr;
            kvo[i][c] = row * 64 + (((c * 4 + lq + row) & 7) << 3);
        }
    const unsigned short* Kb = Kk + base;       // += 64*64 per tile (SGPR)
    const unsigned short* Vb = Vt + base;       // += 64 per tile (SGPR)

    short8 ones;
    #pragma unroll
    for (int i = 0; i < 8; ++i) ones[i] = (short)0x3F80;    // bf16 1.0

    fx4 lacc[2];
    fx4 o[2][4];                                // o[qt][dn]: O^T, row=d, col=q
    #pragma unroll
    for (int qt = 0; qt < 2; ++qt) {
        lacc[qt] = 0.0f;
        #pragma unroll
        for (int dn = 0; dn < 4; ++dn) o[qt][dn] = 0.0f;
    }

    for (int kt = 0; kt < 32; ++kt) {
        __syncthreads();                        // prev tile reads done
        #pragma unroll
        for (int c2 = 0; c2 < 2; ++c2) {
            ld_lds16(Kb + kg[c2], &Ks[lo[c2]]);
            ld_lds16(Vb + vg[c2], &Vs[lo[c2]]);
        }
        Kb += 64 * 64; Vb += 64;
        __syncthreads();                        // drains vmcnt(0)

        short8 kf[4][2], vf[4][2];
        #pragma unroll
        for (int kn = 0; kn < 4; ++kn)
            #pragma unroll
            for (int c = 0; c < 2; ++c)
                kf[kn][c] = *(const short8*)&Ks[kvo[kn][c]];
        #pragma unroll
        for (int dn = 0; dn < 4; ++dn)
            #pragma unroll
            for (int c = 0; c < 2; ++c)
                vf[dn][c] = *(const short8*)&Vs[kvo[dn][c]];

        #pragma unroll
        for (int qt = 0; qt < 2; ++qt) {
            #pragma unroll
            for (int kn = 0; kn < 4; ++kn) {
                fx4 s = 0.0f;
                s = __builtin_amdgcn_mfma_f32_16x16x32_bf16(
                    kf[kn][0], qf[qt][0], s, 0, 0, 0);
                s = __builtin_amdgcn_mfma_f32_16x16x32_bf16(
                    kf[kn][1], qf[qt][1], s, 0, 0, 0);
                float p0 = fexp2(s[0]);
                float p1 = fexp2(s[1]);
                float p2 = fexp2(s[2]);
                float p3 = fexp2(s[3]);
                uint2 pk;
                pk.x = pack_trunc(p0, p1);
                pk.y = pack_trunc(p2, p3);
                *(uint2*)&Ps[w][lr * 72 + kn * 16 + lq * 4] = pk;
            }
            short8 pf0 = *(const short8*)&Ps[w][lr * 72 + lq * 8];
            short8 pf1 = *(const short8*)&Ps[w][lr * 72 + 32 + lq * 8];
            lacc[qt] = __builtin_amdgcn_mfma_f32_16x16x32_bf16(
                ones, pf0, lacc[qt], 0, 0, 0);
            lacc[qt] = __builtin_amdgcn_mfma_f32_16x16x32_bf16(
                ones, pf1, lacc[qt], 0, 0, 0);
            #pragma unroll
            for (int dn = 0; dn < 4; ++dn) {
                o[qt][dn] = __builtin_amdgcn_mfma_f32_16x16x32_bf16(
                    vf[dn][0], pf0, o[qt][dn], 0, 0, 0);
                o[qt][dn] = __builtin_amdgcn_mfma_f32_16x16x32_bf16(
                    vf[dn][1], pf1, o[qt][dn], 0, 0, 0);
            }
        }
    }

    // Normalize (l in same col=q layout as o: no shuffles) and write Y[B,T,C].
    #pragma unroll
    for (int qt = 0; qt < 2; ++qt) {
        float inv = __builtin_amdgcn_rcpf(lacc[qt][0]);
        int qg = q0 + qt * 16 + lr;
        #pragma unroll
        for (int dn = 0; dn < 4; ++dn) {
            ushort4 ov;
            ov.x = f2bf(o[qt][dn][0] * inv);
            ov.y = f2bf(o[qt][dn][1] * inv);
            ov.z = f2bf(o[qt][dn][2] * inv);
            ov.w = f2bf(o[qt][dn][3] * inv);
            *(ushort4*)&Y[((size_t)(batch * 2048 + qg)) * 1024 +
                          head * 64 + dn * 16 + lq * 4] = ov;
        }
    }
}

// ---------------------------------------------------------------------------
extern "C" void kernel_launch(void* const* d_in, const int* in_sizes, int n_in,
                              void* d_out, int out_size, void* d_ws, size_t ws_size,
                              hipStream_t stream)
{
    const float* x      = (const float*)d_in[0];
    const float* ln1_g  = (const float*)d_in[1];
    const float* ln1_b  = (const float*)d_in[2];
    const float* w_qkv  = (const float*)d_in[3];
    const float* b_qkv  = (const float*)d_in[4];
    const float* w_ap   = (const float*)d_in[5];
    const float* b_ap   = (const float*)d_in[6];
    const float* ln2_g  = (const float*)d_in[7];
    const float* ln2_b  = (const float*)d_in[8];
    const float* w_fc   = (const float*)d_in[9];
    const float* b_fc   = (const float*)d_in[10];
    const float* w_proj = (const float*)d_in[11];
    const float* b_proj = (const float*)d_in[12];
    float* out = (float*)d_out;

    char* ws = (char*)d_ws;
    unsigned short* wT_qkv = (unsigned short*)(ws + 0);          // 3072x1024 bf16
    unsigned short* wT_ap  = (unsigned short*)(ws + 6291456);    // 1024x1024
    unsigned short* wT_fc  = (unsigned short*)(ws + 8388608);    // 4096x1024
    unsigned short* wT_pr  = (unsigned short*)(ws + 16777216);   // 1024x4096
    float*          x2     = (float*)(ws + 25165824);            // 8192x1024 f32
    unsigned short* Abuf   = (unsigned short*)(ws + 58720256);   // 8192x1024 bf16
    unsigned short* Qb     = (unsigned short*)(ws + 75497472);
    unsigned short* Kb     = (unsigned short*)(ws + 75497472 + 16777216);
    unsigned short* Vtb    = (unsigned short*)(ws + 75497472 + 33554432);
    unsigned short* H3     = (unsigned short*)(ws + 75497472);   // aliases Q/K/Vt

    transpose_all<<<12288, dim3(32, 8), 0, stream>>>(
        w_qkv, wT_qkv, w_ap, wT_ap, w_fc, wT_fc, w_proj, wT_pr);

    // LN1 -> h1 (bf16)
    layernorm_bf16<<<8192, 256, 0, stream>>>(x, ln1_g, ln1_b, Abuf);
    // QKV GEMM, scatter Q(scaled)/K/Vt   (row-major: B panels XCD-local)
    gemm_bt<0, false><<<dim3(24, 64), 256, 0, stream>>>(
        Abuf, wT_qkv, b_qkv, nullptr, Qb, Kb, Vtb, 8192, 3072, 1024);
    // attention -> Y (reuses Abuf)
    flash_attn<<<dim3(16, 64), 256, 0, stream>>>(Qb, Kb, Vtb, Abuf);
    // attn proj + residual -> x2 (f32)   (column-major: A panels XCD-local)
    gemm_bt<1, true><<<dim3(64, 8), 256, 0, stream>>>(
        Abuf, wT_ap, b_ap, x, x2, nullptr, nullptr, 8192, 1024, 1024);
    // LN2 -> h2 (bf16, reuses Abuf)
    layernorm_bf16<<<8192, 256, 0, stream>>>(x2, ln2_g, ln2_b, Abuf);
    // FC + GELU -> h3 (bf16, aliases Q/K/Vt region)  (row-major)
    gemm_bt<2, false><<<dim3(32, 64), 256, 0, stream>>>(
        Abuf, wT_fc, b_fc, nullptr, H3, nullptr, nullptr, 8192, 4096, 1024);
    // proj + residual -> out (f32)       (column-major: A=H3 64MB XCD-local)
    gemm_bt<1, true><<<dim3(64, 8), 256, 0, stream>>>(
        H3, wT_pr, b_proj, x2, out, nullptr, nullptr, 8192, 1024, 4096);
}